// Round 16
// baseline (130.630 us; speedup 1.0000x reference)
//
#include <hip/hip_runtime.h>

typedef __bf16 bf16x8 __attribute__((ext_vector_type(8)));
typedef __bf16 bf16x4 __attribute__((ext_vector_type(4)));
typedef float  f32x4  __attribute__((ext_vector_type(4)));
typedef float  f32x16 __attribute__((ext_vector_type(16)));
typedef unsigned u32x2 __attribute__((ext_vector_type(2)));
typedef unsigned u32x4 __attribute__((ext_vector_type(4)));

#define T_SEQ 2048
#define NH    16
#define HD    64
#define EMB   1024
#define BATCH 2
// 1/sqrt(HD) * log2(e) — softmax in base 2
#define QSCALE 0.18033688f

__device__ __forceinline__ void gload_lds16(const void* g, void* lds) {
  __builtin_amdgcn_global_load_lds(
      (__attribute__((address_space(1))) void*)(g),
      (__attribute__((address_space(3))) void*)(lds), 16, 0, 0);
}

__device__ __forceinline__ f32x16 mfma32(bf16x8 a, bf16x8 b, f32x16 c) {
  return __builtin_amdgcn_mfma_f32_32x32x16_bf16(a, b, c, 0, 0, 0);
}

__device__ __forceinline__ f32x4 mfma16(bf16x8 a, bf16x8 b, f32x4 c) {
  return __builtin_amdgcn_mfma_f32_16x16x32_bf16(a, b, c, 0, 0, 0);
}

__device__ __forceinline__ unsigned cvtpk(float lo, float hi) {
  unsigned short a = __builtin_bit_cast(unsigned short, (__bf16)lo);
  unsigned short b = __builtin_bit_cast(unsigned short, (__bf16)hi);
  return (unsigned)a | ((unsigned)b << 16);
}

// ---- fp32 -> bf16 straight convert ----
__global__ __launch_bounds__(256) void cvt_bf16(const float* __restrict__ in,
                                                __bf16* __restrict__ out, int n) {
  int i = (blockIdx.x * 256 + threadIdx.x) * 8;
  if (i >= n) return;
  f32x4 a = *(const f32x4*)(in + i);
  f32x4 b = *(const f32x4*)(in + i + 4);
  bf16x8 v;
  v[0] = (__bf16)a[0]; v[1] = (__bf16)a[1]; v[2] = (__bf16)a[2]; v[3] = (__bf16)a[3];
  v[4] = (__bf16)b[0]; v[5] = (__bf16)b[1]; v[6] = (__bf16)b[2]; v[7] = (__bf16)b[3];
  *(bf16x8*)(out + i) = v;
}

// ---- fp32 [rows][cols] -> bf16 [cols][rows] ----
__global__ __launch_bounds__(256) void transpose_cvt(const float* __restrict__ in,
                                                     __bf16* __restrict__ out,
                                                     int rows, int cols) {
  __shared__ float tile[32][33];
  int c0 = blockIdx.x * 32, r0 = blockIdx.y * 32;
  int tx = threadIdx.x & 31, ty = threadIdx.x >> 5;
#pragma unroll
  for (int j = 0; j < 32; j += 8)
    tile[ty + j][tx] = in[(size_t)(r0 + ty + j) * cols + c0 + tx];
  __syncthreads();
#pragma unroll
  for (int j = 0; j < 32; j += 8)
    out[(size_t)(c0 + ty + j) * rows + r0 + tx] = (__bf16)tile[tx][ty + j];
}

// ---- gemm64: C[M,N] = A[M,K]*Bt[N,K]^T, 128(M)x64(N) tile, BK=32 ----
// The proj-proven structure (r13: ~860 TF) applied to both GEMMs.
// Triple-buffered LDS, counted vmcnt(3), both-sides XOR swizzle.
// Grid: (N/64, M/128) — qkv: 48x32 = 1536 blocks (4+/CU), proj: 16x32 = 512.
// MODE 0: QKV scatter epilogue (vectorized V stores). MODE 1: bias + f32.
template <int MODE>
__global__ __launch_bounds__(256) void gemm64(
    const __bf16* __restrict__ A, const __bf16* __restrict__ Bt, int K,
    __bf16* __restrict__ Qo, __bf16* __restrict__ Ko, __bf16* __restrict__ Vt,
    const float* __restrict__ bias, float* __restrict__ Cout) {
  __shared__ alignas(16) __bf16 sA[3][128 * 32];
  __shared__ alignas(16) __bf16 sB[3][64 * 32];
  const int tid = threadIdx.x;
  const int w = tid >> 6, l = tid & 63;
  const int m0 = blockIdx.y * 128, n0 = blockIdx.x * 64;
  const int lc = l & 15, lu = l >> 4;
  const int mw = (w >> 1) * 64, nw = (w & 1) * 32;
  const int rA = l >> 2;
  const int usw = (((l & 3) ^ ((rA >> 1) & 3))) * 8;
  const int rsw = (lu ^ ((lc >> 1) & 3)) * 8;

  f32x4 acc[4][2] = {};

  // 3 gload_lds16/thread/stage: 2 for A (128 rows), 1 for B (64 rows)
  auto stage = [&](int buf, int kt) {
#pragma unroll
    for (int i = 0; i < 2; ++i) {
      int rr = (w * 2 + i) * 16;
      gload_lds16(A + (size_t)(m0 + rr + rA) * K + kt + usw, &sA[buf][rr * 32]);
    }
    gload_lds16(Bt + (size_t)(n0 + w * 16 + rA) * K + kt + usw,
                &sB[buf][w * 16 * 32]);
  };

  const int NT = K >> 5;
  stage(0, 0);
  stage(1, 32);

  int bi = 0;
  for (int i = 0; i < NT; ++i) {
    if (i == NT - 1) { asm volatile("s_waitcnt vmcnt(0)" ::: "memory"); }
    else             { asm volatile("s_waitcnt vmcnt(3)" ::: "memory"); }
    __builtin_amdgcn_s_barrier();
    __builtin_amdgcn_sched_barrier(0);

    if (i + 2 < NT) {
      int bs = bi + 2; if (bs >= 3) bs -= 3;
      stage(bs, (i + 2) * 32);
    }

    bf16x8 af[4], bfr[2];
#pragma unroll
    for (int f = 0; f < 4; ++f)
      af[f] = *(const bf16x8*)(&sA[bi][(mw + f * 16 + lc) * 32 + rsw]);
#pragma unroll
    for (int f = 0; f < 2; ++f)
      bfr[f] = *(const bf16x8*)(&sB[bi][(nw + f * 16 + lc) * 32 + rsw]);
#pragma unroll
    for (int mf = 0; mf < 4; ++mf)
#pragma unroll
      for (int nf = 0; nf < 2; ++nf)
        acc[mf][nf] = mfma16(af[mf], bfr[nf], acc[mf][nf]);

    if (++bi >= 3) bi = 0;
  }

#pragma unroll
  for (int mf = 0; mf < 4; ++mf) {
#pragma unroll
    for (int nf = 0; nf < 2; ++nf) {
      if (MODE == 0) {
        int ng = n0 + nw + nf * 16 + lc;
        int part = ng >> 10;
        int h = (ng >> 6) & 15;
        int d = ng & 63;
        int mg0 = m0 + mw + mf * 16 + lu * 4;
        int b = mg0 >> 11;
        int t0 = mg0 & 2047;
        if (part == 2) {
          bf16x4 v4;
#pragma unroll
          for (int r = 0; r < 4; ++r) v4[r] = (__bf16)acc[mf][nf][r];
          *(bf16x4*)(Vt + ((size_t)(b * NH + h) * HD + d) * T_SEQ + t0) = v4;
        } else if (part == 0) {
#pragma unroll
          for (int r = 0; r < 4; ++r)
            Qo[((size_t)(b * NH + h) * T_SEQ + t0 + r) * HD + d] =
                (__bf16)(acc[mf][nf][r] * QSCALE);
        } else {
#pragma unroll
          for (int r = 0; r < 4; ++r)
            Ko[((size_t)(b * NH + h) * T_SEQ + t0 + r) * HD + d] =
                (__bf16)acc[mf][nf][r];
        }
      } else {
#pragma unroll
        for (int r = 0; r < 4; ++r) {
          int mg = m0 + mw + mf * 16 + lu * 4 + r;
          int ng = n0 + nw + nf * 16 + lc;
          Cout[(size_t)mg * EMB + ng] = acc[mf][nf][r] + bias[ng];
        }
      }
    }
  }
}

// ---- causal mask on one S^T 32x32 tile (rows=k, col=q per lane) ----
__device__ __forceinline__ void cmask32(f32x16& s0, int k0, int hi, int q) {
#pragma unroll
  for (int r = 0; r < 16; ++r) {
    int kk = k0 + 4 * hi + (r & 3) + 8 * (r >> 2);
    if (kk > q) s0[r] = -1e30f;
  }
}

// ---- in-register online softmax + P packing, 32-k tile (T12/T13) ----
__device__ __forceinline__ void softmax_pack32(
    f32x16& s0, f32x16& o0, f32x16& o1,
    float& m, float& ls, u32x4 (&pf)[2]) {
  float mx[8];
#pragma unroll
  for (int r = 0; r < 8; ++r) mx[r] = fmaxf(s0[r], s0[r + 8]);
#pragma unroll
  for (int st = 4; st > 0; st >>= 1)
#pragma unroll
    for (int r = 0; r < 8; ++r) if (r < st) mx[r] = fmaxf(mx[r], mx[r + st]);
  float pmax = fmaxf(mx[0], __shfl_xor(mx[0], 32));
  if (!__all(pmax <= m + 8.0f)) {       // defer-max rescale
    float mn = fmaxf(m, pmax);
    float al = __builtin_amdgcn_exp2f(m - mn);
    m = mn;
    ls *= al;
#pragma unroll
    for (int r = 0; r < 16; ++r) { o0[r] *= al; o1[r] *= al; }
  }
  float ps = 0.f;
  f32x16 p;
#pragma unroll
  for (int r = 0; r < 16; ++r) { p[r] = __builtin_amdgcn_exp2f(s0[r] - m); ps += p[r]; }
  ps += __shfl_xor(ps, 32);
  ls += ps;
#pragma unroll
  for (int kh = 0; kh < 2; ++kh) {
    unsigned c01 = cvtpk(p[kh * 8 + 0], p[kh * 8 + 1]);
    unsigned c23 = cvtpk(p[kh * 8 + 2], p[kh * 8 + 3]);
    unsigned c45 = cvtpk(p[kh * 8 + 4], p[kh * 8 + 5]);
    unsigned c67 = cvtpk(p[kh * 8 + 6], p[kh * 8 + 7]);
    u32x2 a = __builtin_amdgcn_permlane32_swap(c01, c45, false, false);
    u32x2 c = __builtin_amdgcn_permlane32_swap(c23, c67, false, false);
    u32x4 r; r[0] = a[0]; r[1] = c[0]; r[2] = a[1]; r[3] = c[1];
    pf[kh] = r;
  }
}

__device__ __forceinline__ void dump_state(float* mo, float* mm, int reg, int l,
                                           const f32x16& o0, const f32x16& o1,
                                           float m, float ls) {
  float* po = mo + reg * 2048 + l;
#pragma unroll
  for (int r = 0; r < 16; ++r) { po[r * 64] = o0[r]; po[(16 + r) * 64] = o1[r]; }
  mm[reg * 128 + l] = m;
  mm[reg * 128 + 64 + l] = ls;
}

__device__ __forceinline__ void merge_write(const float* mo, const float* mm,
                                            int reg, int l, int hi,
                                            const f32x16& o0, const f32x16& o1,
                                            float m, float ls,
                                            __bf16* O, size_t rowbase) {
  float m1 = mm[reg * 128 + l];
  float l1 = mm[reg * 128 + 64 + l];
  float mn = fmaxf(m, m1);
  float a0 = __builtin_amdgcn_exp2f(m - mn);
  float a1 = __builtin_amdgcn_exp2f(m1 - mn);
  float inv = 1.f / (ls * a0 + l1 * a1);
  const float* po = mo + reg * 2048 + l;
#pragma unroll
  for (int dt = 0; dt < 2; ++dt) {
    const f32x16& ov = dt ? o1 : o0;
#pragma unroll
    for (int rg = 0; rg < 4; ++rg) {
      bf16x4 vv;
#pragma unroll
      for (int j = 0; j < 4; ++j) {
        int r = rg * 4 + j;
        float oth = po[(dt * 16 + r) * 64];
        vv[j] = (__bf16)((ov[r] * a0 + oth * a1) * inv);
      }
      int d = dt * 32 + rg * 8 + 4 * hi;
      *(bf16x4*)(O + rowbase + d) = vv;
    }
  }
}

// ---- causal flash attention: 8-wave blocks, one role per wave,
//      TRIPLE-buffered K/V slots + counted vmcnt(2) (round-11, 50.9us) ----
__global__ __launch_bounds__(512, 4) void attn(
    const __bf16* __restrict__ Q,   // [BH][T][D] pre-scaled by QSCALE
    const __bf16* __restrict__ K,   // [BH][T][D]
    const __bf16* __restrict__ Vt,  // [BH][D][T]
    __bf16* __restrict__ O) {       // [B*T][EMB]
  __shared__ alignas(16) __bf16 sKV[12][32 * 64];  // K: buf*2+par (0..5), V: 6+...
  __shared__ alignas(16) float mls[4 * 2 * 64];

  const int x = blockIdx.x, bh = blockIdx.y;
  const int tid = threadIdx.x, w = tid >> 6, l = tid & 63;
  const int lq = l & 31, hi = l >> 5;
  const int c  = w >> 2;
  const int st = (w >> 1) & 1;
  const int gc = w & 1;
  const int kind = w >> 2, sp = (w >> 1) & 1, shf = w & 1;

  const __bf16* Qh = Q + (size_t)bh * T_SEQ * HD;
  const __bf16* Kh = K + (size_t)bh * T_SEQ * HD;
  const __bf16* Vh = Vt + (size_t)bh * HD * T_SEQ;

  const int C = (c == 0) ? (31 - x) : x;
  const int q0 = C * 64 + st * 32;
  const int diagT = 2 * C + st;
  const int nsup = 32 - x;

  bf16x8 qf[4];
#pragma unroll
  for (int dc = 0; dc < 4; ++dc)
    qf[dc] = *(const bf16x8*)(Qh + (size_t)(q0 + lq) * HD + dc * 16 + hi * 8);

  f32x16 o0 = {}, o1 = {};
  float m = -1e30f, ls = 0.f;

  const int r8 = l >> 3;
  const int kswz = ((l & 7) ^ r8) * 8;
  const int r4 = l >> 2;
  const int vswz = ((l & 3) ^ (r4 & 3)) * 8;

  auto stage = [&](int buf, int ss) {
    int t = 2 * ss + sp;
    int k0s = t * 32;
    if (kind == 0) {       // K tile: 32 rows(k) x 64(d); half shf = 16 rows
      __bf16* dst = &sKV[buf * 2 + sp][shf * 16 * 64];
#pragma unroll
      for (int i = 0; i < 2; ++i)
        gload_lds16(Kh + (size_t)(k0s + shf * 16 + i * 8 + r8) * HD + kswz,
                    dst + i * 512);
    } else {               // V^T tile: 64 rows(d) x 32(k); half shf = 32 rows
      __bf16* dst = &sKV[6 + buf * 2 + sp][shf * 32 * 32];
#pragma unroll
      for (int i = 0; i < 2; ++i)
        gload_lds16(Vh + (size_t)(shf * 32 + i * 16 + r4) * T_SEQ + k0s + vswz,
                    dst + i * 512);
    }
  };

  auto kfrag = [&](const __bf16* b, int row, int u) -> bf16x8 {
    return *(const bf16x8*)(b + row * 64 + ((u ^ (row & 7)) << 3));
  };
  auto vfrag = [&](const __bf16* b, int row, int u) -> bf16x8 {
    return *(const bf16x8*)(b + row * 32 + ((u ^ (row & 3)) << 3));
  };

  stage(0, 0);
  stage(1, 1);           // nsup >= 17, always valid

  int buf = 0;
  for (int ss = 0; ss < nsup; ++ss) {
    // wait this superstep's OWN 2 loads; next superstep's stay in flight
    if (ss + 1 < nsup) { asm volatile("s_waitcnt vmcnt(2)" ::: "memory"); }
    else               { asm volatile("s_waitcnt vmcnt(0)" ::: "memory"); }
    __builtin_amdgcn_s_barrier();
    __builtin_amdgcn_sched_barrier(0);

    if (ss + 2 < nsup) {
      int bs = buf + 2; if (bs >= 3) bs -= 3;
      stage(bs, ss + 2);
    }

    const int tg = 2 * ss + gc;
    if (tg <= diagT) {
      const __bf16* sKb = &sKV[buf * 2 + gc][0];
      const __bf16* sVb = &sKV[6 + buf * 2 + gc][0];
      f32x16 s = {};
#pragma unroll
      for (int dc = 0; dc < 4; ++dc)
        s = mfma32(kfrag(sKb, lq, dc * 2 + hi), qf[dc], s);
      if (tg == diagT) cmask32(s, tg * 32, hi, q0 + lq);
      u32x4 pf[2];
      softmax_pack32(s, o0, o1, m, ls, pf);
#pragma unroll
      for (int ks = 0; ks < 2; ++ks) {
        bf16x8 vf0 = vfrag(sVb, lq, ks * 2 + hi);
        bf16x8 vf1 = vfrag(sVb, 32 + lq, ks * 2 + hi);
        bf16x8 pa = __builtin_bit_cast(bf16x8, pf[ks]);
        o0 = mfma32(vf0, pa, o0);
        o1 = mfma32(vf1, pa, o1);
      }
    }
    if (++buf >= 3) buf = 0;
  }

  // ---- cross-parity merge (gc=1 dumps, gc=0 merges + stores) ----
  __syncthreads();                  // full drain before aliasing sKV
  float* mo = (float*)&sKV[0][0];   // 4 regions x 2048 f32 = 32 KiB
  const int reg = c * 2 + st;
  if (gc == 1) dump_state(mo, mls, reg, l, o0, o1, m, ls);
  __syncthreads();
  if (gc == 0) {
    const int b = bh >> 4, h = bh & 15;
    size_t row = (size_t)(b * T_SEQ + q0 + lq) * EMB + h * HD;
    merge_write(mo, mls, reg, l, hi, o0, o1, m, ls, O, row);
  }
}

extern "C" void kernel_launch(void* const* d_in, const int* in_sizes, int n_in,
                              void* d_out, int out_size, void* d_ws, size_t ws_size,
                              hipStream_t stream) {
  const float* x      = (const float*)d_in[0];
  const float* w_qkv  = (const float*)d_in[1];
  const float* w_proj = (const float*)d_in[2];
  const float* b_proj = (const float*)d_in[3];
  float* out = (float*)d_out;

  char* ws = (char*)d_ws;
  __bf16* xb     = (__bf16*)(ws);                     // 8 MiB
  __bf16* wqkvT  = (__bf16*)(ws + (8u  << 20));       // 6 MiB
  __bf16* wprojT = (__bf16*)(ws + (14u << 20));       // 2 MiB
  __bf16* Qw     = (__bf16*)(ws + (16u << 20));       // 8 MiB
  __bf16* Kw     = (__bf16*)(ws + (24u << 20));       // 8 MiB
  __bf16* Vw     = (__bf16*)(ws + (32u << 20));       // 8 MiB
  __bf16* Ow     = xb;                                // reuse after QKV GEMM

  cvt_bf16<<<2048, 256, 0, stream>>>(x, xb, 4096 * 1024);
  transpose_cvt<<<dim3(3072 / 32, 1024 / 32), 256, 0, stream>>>(w_qkv, wqkvT, 1024, 3072);
  transpose_cvt<<<dim3(1024 / 32, 1024 / 32), 256, 0, stream>>>(w_proj, wprojT, 1024, 1024);

  gemm64<0><<<dim3(3072 / 64, 4096 / 128), 256, 0, stream>>>(
      xb, wqkvT, 1024, Qw, Kw, Vw, nullptr, nullptr);

  attn<<<dim3(16, BATCH * NH), 512, 0, stream>>>(Qw, Kw, Vw, Ow);

  gemm64<1><<<dim3(1024 / 64, 4096 / 128), 256, 0, stream>>>(
      Ow, wprojT, 1024, nullptr, nullptr, nullptr, b_proj, out);
}

// Round 17
// 118.856 us; speedup vs baseline: 1.0991x; 1.0991x over previous
//
#include <hip/hip_runtime.h>

typedef __bf16 bf16x8 __attribute__((ext_vector_type(8)));
typedef __bf16 bf16x4 __attribute__((ext_vector_type(4)));
typedef float  f32x4  __attribute__((ext_vector_type(4)));
typedef float  f32x16 __attribute__((ext_vector_type(16)));
typedef unsigned u32x2 __attribute__((ext_vector_type(2)));
typedef unsigned u32x4 __attribute__((ext_vector_type(4)));

#define T_SEQ 2048
#define NH    16
#define HD    64
#define EMB   1024
#define BATCH 2
// 1/sqrt(HD) * log2(e) — softmax in base 2
#define QSCALE 0.18033688f

__device__ __forceinline__ void gload_lds16(const void* g, void* lds) {
  __builtin_amdgcn_global_load_lds(
      (__attribute__((address_space(1))) void*)(g),
      (__attribute__((address_space(3))) void*)(lds), 16, 0, 0);
}

__device__ __forceinline__ f32x16 mfma32(bf16x8 a, bf16x8 b, f32x16 c) {
  return __builtin_amdgcn_mfma_f32_32x32x16_bf16(a, b, c, 0, 0, 0);
}

__device__ __forceinline__ f32x4 mfma16(bf16x8 a, bf16x8 b, f32x4 c) {
  return __builtin_amdgcn_mfma_f32_16x16x32_bf16(a, b, c, 0, 0, 0);
}

__device__ __forceinline__ unsigned cvtpk(float lo, float hi) {
  unsigned short a = __builtin_bit_cast(unsigned short, (__bf16)lo);
  unsigned short b = __builtin_bit_cast(unsigned short, (__bf16)hi);
  return (unsigned)a | ((unsigned)b << 16);
}

// ---- fp32 -> bf16 straight convert ----
__global__ __launch_bounds__(256) void cvt_bf16(const float* __restrict__ in,
                                                __bf16* __restrict__ out, int n) {
  int i = (blockIdx.x * 256 + threadIdx.x) * 8;
  if (i >= n) return;
  f32x4 a = *(const f32x4*)(in + i);
  f32x4 b = *(const f32x4*)(in + i + 4);
  bf16x8 v;
  v[0] = (__bf16)a[0]; v[1] = (__bf16)a[1]; v[2] = (__bf16)a[2]; v[3] = (__bf16)a[3];
  v[4] = (__bf16)b[0]; v[5] = (__bf16)b[1]; v[6] = (__bf16)b[2]; v[7] = (__bf16)b[3];
  *(bf16x8*)(out + i) = v;
}

// ---- fp32 [rows][cols] -> bf16 [cols][rows] ----
__global__ __launch_bounds__(256) void transpose_cvt(const float* __restrict__ in,
                                                     __bf16* __restrict__ out,
                                                     int rows, int cols) {
  __shared__ float tile[32][33];
  int c0 = blockIdx.x * 32, r0 = blockIdx.y * 32;
  int tx = threadIdx.x & 31, ty = threadIdx.x >> 5;
#pragma unroll
  for (int j = 0; j < 32; j += 8)
    tile[ty + j][tx] = in[(size_t)(r0 + ty + j) * cols + c0 + tx];
  __syncthreads();
#pragma unroll
  for (int j = 0; j < 32; j += 8)
    out[(size_t)(c0 + ty + j) * rows + r0 + tx] = (__bf16)tile[tx][ty + j];
}

// ---- gemm_bt: C[M,N] = A[M,K] * Bt[N,K]^T, 128x128 tile, BK=32, 4 waves ----
// Triple-buffered LDS, counted vmcnt(4); both-sides XOR swizzle.
// MODE 0: QKV scatter epilogue with vectorized V-part stores (r14/r15 proven).
template <int MODE>
__global__ __launch_bounds__(256) void gemm_bt(
    const __bf16* __restrict__ A, const __bf16* __restrict__ Bt, int K,
    __bf16* __restrict__ Qo, __bf16* __restrict__ Ko, __bf16* __restrict__ Vt,
    const float* __restrict__ bias, float* __restrict__ Cout) {
  __shared__ alignas(16) __bf16 sA[3][128 * 32];
  __shared__ alignas(16) __bf16 sB[3][128 * 32];
  const int tid = threadIdx.x;
  const int w = tid >> 6, l = tid & 63;
  const int m0 = blockIdx.y * 128, n0 = blockIdx.x * 128;
  const int lc = l & 15, lu = l >> 4;
  const int mw = (w >> 1) * 64, nw = (w & 1) * 64;
  const int rA = l >> 2;
  const int usw = (((l & 3) ^ ((rA >> 1) & 3))) * 8;
  const int rsw = (lu ^ ((lc >> 1) & 3)) * 8;

  f32x4 acc[4][4] = {};

  auto stage = [&](int buf, int kt) {
#pragma unroll
    for (int i = 0; i < 2; ++i) {
      int rr = (w * 2 + i) * 16;
      gload_lds16(A  + (size_t)(m0 + rr + rA) * K + kt + usw, &sA[buf][rr * 32]);
      gload_lds16(Bt + (size_t)(n0 + rr + rA) * K + kt + usw, &sB[buf][rr * 32]);
    }
  };

  const int NT = K >> 5;
  stage(0, 0);
  stage(1, 32);

  int bi = 0;
  for (int i = 0; i < NT; ++i) {
    if (i == NT - 1) { asm volatile("s_waitcnt vmcnt(0)" ::: "memory"); }
    else             { asm volatile("s_waitcnt vmcnt(4)" ::: "memory"); }
    __builtin_amdgcn_s_barrier();
    __builtin_amdgcn_sched_barrier(0);

    if (i + 2 < NT) {
      int bs = bi + 2; if (bs >= 3) bs -= 3;
      stage(bs, (i + 2) * 32);
    }

    bf16x8 af[4], bfr[4];
#pragma unroll
    for (int f = 0; f < 4; ++f) {
      af[f]  = *(const bf16x8*)(&sA[bi][(mw + f * 16 + lc) * 32 + rsw]);
      bfr[f] = *(const bf16x8*)(&sB[bi][(nw + f * 16 + lc) * 32 + rsw]);
    }
#pragma unroll
    for (int mf = 0; mf < 4; ++mf)
#pragma unroll
      for (int nf = 0; nf < 4; ++nf)
        acc[mf][nf] = mfma16(af[mf], bfr[nf], acc[mf][nf]);

    if (++bi >= 3) bi = 0;
  }

#pragma unroll
  for (int mf = 0; mf < 4; ++mf) {
#pragma unroll
    for (int nf = 0; nf < 4; ++nf) {
      if (MODE == 0) {
        int ng = n0 + nw + nf * 16 + lc;
        int part = ng >> 10;
        int h = (ng >> 6) & 15;
        int d = ng & 63;
        int mg0 = m0 + mw + mf * 16 + lu * 4;
        int b = mg0 >> 11;
        int t0 = mg0 & 2047;
        if (part == 2) {
          bf16x4 v4;
#pragma unroll
          for (int r = 0; r < 4; ++r) v4[r] = (__bf16)acc[mf][nf][r];
          *(bf16x4*)(Vt + ((size_t)(b * NH + h) * HD + d) * T_SEQ + t0) = v4;
        } else if (part == 0) {
#pragma unroll
          for (int r = 0; r < 4; ++r)
            Qo[((size_t)(b * NH + h) * T_SEQ + t0 + r) * HD + d] =
                (__bf16)(acc[mf][nf][r] * QSCALE);
        } else {
#pragma unroll
          for (int r = 0; r < 4; ++r)
            Ko[((size_t)(b * NH + h) * T_SEQ + t0 + r) * HD + d] =
                (__bf16)acc[mf][nf][r];
        }
      } else {
#pragma unroll
        for (int r = 0; r < 4; ++r) {
          int mg = m0 + mw + mf * 16 + lu * 4 + r;
          int ng = n0 + nw + nf * 16 + lc;
          Cout[(size_t)mg * EMB + ng] = acc[mf][nf][r] + bias[ng];
        }
      }
    }
  }
}

// ---- gemm_proj: C[M,N] = A[M,K]*Bt[N,K]^T + bias, 128(M)x64(N) tile ----
__global__ __launch_bounds__(256) void gemm_proj(
    const __bf16* __restrict__ A, const __bf16* __restrict__ Bt, int K,
    const float* __restrict__ bias, float* __restrict__ Cout) {
  __shared__ alignas(16) __bf16 sA[3][128 * 32];
  __shared__ alignas(16) __bf16 sB[3][64 * 32];
  const int tid = threadIdx.x;
  const int w = tid >> 6, l = tid & 63;
  const int m0 = blockIdx.y * 128, n0 = blockIdx.x * 64;
  const int lc = l & 15, lu = l >> 4;
  const int mw = (w >> 1) * 64, nw = (w & 1) * 32;
  const int rA = l >> 2;
  const int usw = (((l & 3) ^ ((rA >> 1) & 3))) * 8;
  const int rsw = (lu ^ ((lc >> 1) & 3)) * 8;

  f32x4 acc[4][2] = {};

  auto stage = [&](int buf, int kt) {
#pragma unroll
    for (int i = 0; i < 2; ++i) {
      int rr = (w * 2 + i) * 16;
      gload_lds16(A + (size_t)(m0 + rr + rA) * K + kt + usw, &sA[buf][rr * 32]);
    }
    gload_lds16(Bt + (size_t)(n0 + w * 16 + rA) * K + kt + usw,
                &sB[buf][w * 16 * 32]);
  };

  const int NT = K >> 5;
  stage(0, 0);
  stage(1, 32);

  int bi = 0;
  for (int i = 0; i < NT; ++i) {
    if (i == NT - 1) { asm volatile("s_waitcnt vmcnt(0)" ::: "memory"); }
    else             { asm volatile("s_waitcnt vmcnt(3)" ::: "memory"); }
    __builtin_amdgcn_s_barrier();
    __builtin_amdgcn_sched_barrier(0);

    if (i + 2 < NT) {
      int bs = bi + 2; if (bs >= 3) bs -= 3;
      stage(bs, (i + 2) * 32);
    }

    bf16x8 af[4], bfr[2];
#pragma unroll
    for (int f = 0; f < 4; ++f)
      af[f] = *(const bf16x8*)(&sA[bi][(mw + f * 16 + lc) * 32 + rsw]);
#pragma unroll
    for (int f = 0; f < 2; ++f)
      bfr[f] = *(const bf16x8*)(&sB[bi][(nw + f * 16 + lc) * 32 + rsw]);
#pragma unroll
    for (int mf = 0; mf < 4; ++mf)
#pragma unroll
      for (int nf = 0; nf < 2; ++nf)
        acc[mf][nf] = mfma16(af[mf], bfr[nf], acc[mf][nf]);

    if (++bi >= 3) bi = 0;
  }

#pragma unroll
  for (int mf = 0; mf < 4; ++mf)
#pragma unroll
    for (int nf = 0; nf < 2; ++nf)
#pragma unroll
      for (int r = 0; r < 4; ++r) {
        int mg = m0 + mw + mf * 16 + lu * 4 + r;
        int ng = n0 + nw + nf * 16 + lc;
        Cout[(size_t)mg * EMB + ng] = acc[mf][nf][r] + bias[ng];
      }
}

// ---- causal mask on one S^T 32x32 tile (rows=k, col=q per lane) ----
__device__ __forceinline__ void cmask32(f32x16& s0, int k0, int hi, int q) {
#pragma unroll
  for (int r = 0; r < 16; ++r) {
    int kk = k0 + 4 * hi + (r & 3) + 8 * (r >> 2);
    if (kk > q) s0[r] = -1e30f;
  }
}

// ---- in-register online softmax + P packing, 32-k tile (T12/T13) ----
__device__ __forceinline__ void softmax_pack32(
    f32x16& s0, f32x16& o0, f32x16& o1,
    float& m, float& ls, u32x4 (&pf)[2]) {
  float mx[8];
#pragma unroll
  for (int r = 0; r < 8; ++r) mx[r] = fmaxf(s0[r], s0[r + 8]);
#pragma unroll
  for (int st = 4; st > 0; st >>= 1)
#pragma unroll
    for (int r = 0; r < 8; ++r) if (r < st) mx[r] = fmaxf(mx[r], mx[r + st]);
  float pmax = fmaxf(mx[0], __shfl_xor(mx[0], 32));
  if (!__all(pmax <= m + 8.0f)) {       // defer-max rescale
    float mn = fmaxf(m, pmax);
    float al = __builtin_amdgcn_exp2f(m - mn);
    m = mn;
    ls *= al;
#pragma unroll
    for (int r = 0; r < 16; ++r) { o0[r] *= al; o1[r] *= al; }
  }
  float ps = 0.f;
  f32x16 p;
#pragma unroll
  for (int r = 0; r < 16; ++r) { p[r] = __builtin_amdgcn_exp2f(s0[r] - m); ps += p[r]; }
  ps += __shfl_xor(ps, 32);
  ls += ps;
#pragma unroll
  for (int kh = 0; kh < 2; ++kh) {
    unsigned c01 = cvtpk(p[kh * 8 + 0], p[kh * 8 + 1]);
    unsigned c23 = cvtpk(p[kh * 8 + 2], p[kh * 8 + 3]);
    unsigned c45 = cvtpk(p[kh * 8 + 4], p[kh * 8 + 5]);
    unsigned c67 = cvtpk(p[kh * 8 + 6], p[kh * 8 + 7]);
    u32x2 a = __builtin_amdgcn_permlane32_swap(c01, c45, false, false);
    u32x2 c = __builtin_amdgcn_permlane32_swap(c23, c67, false, false);
    u32x4 r; r[0] = a[0]; r[1] = c[0]; r[2] = a[1]; r[3] = c[1];
    pf[kh] = r;
  }
}

__device__ __forceinline__ void dump_state(float* mo, float* mm, int reg, int l,
                                           const f32x16& o0, const f32x16& o1,
                                           float m, float ls) {
  float* po = mo + reg * 2048 + l;
#pragma unroll
  for (int r = 0; r < 16; ++r) { po[r * 64] = o0[r]; po[(16 + r) * 64] = o1[r]; }
  mm[reg * 128 + l] = m;
  mm[reg * 128 + 64 + l] = ls;
}

__device__ __forceinline__ void merge_write(const float* mo, const float* mm,
                                            int reg, int l, int hi,
                                            const f32x16& o0, const f32x16& o1,
                                            float m, float ls,
                                            __bf16* O, size_t rowbase) {
  float m1 = mm[reg * 128 + l];
  float l1 = mm[reg * 128 + 64 + l];
  float mn = fmaxf(m, m1);
  float a0 = __builtin_amdgcn_exp2f(m - mn);
  float a1 = __builtin_amdgcn_exp2f(m1 - mn);
  float inv = 1.f / (ls * a0 + l1 * a1);
  const float* po = mo + reg * 2048 + l;
#pragma unroll
  for (int dt = 0; dt < 2; ++dt) {
    const f32x16& ov = dt ? o1 : o0;
#pragma unroll
    for (int rg = 0; rg < 4; ++rg) {
      bf16x4 vv;
#pragma unroll
      for (int j = 0; j < 4; ++j) {
        int r = rg * 4 + j;
        float oth = po[(dt * 16 + r) * 64];
        vv[j] = (__bf16)((ov[r] * a0 + oth * a1) * inv);
      }
      int d = dt * 32 + rg * 8 + 4 * hi;
      *(bf16x4*)(O + rowbase + d) = vv;
    }
  }
}

// ---- causal flash attention: 8-wave blocks, one role per wave,
//      triple-buffered K/V slots + counted vmcnt(2) (r11) + T5 setprio ----
__global__ __launch_bounds__(512, 4) void attn(
    const __bf16* __restrict__ Q,   // [BH][T][D] pre-scaled by QSCALE
    const __bf16* __restrict__ K,   // [BH][T][D]
    const __bf16* __restrict__ Vt,  // [BH][D][T]
    __bf16* __restrict__ O) {       // [B*T][EMB]
  __shared__ alignas(16) __bf16 sKV[12][32 * 64];  // K: buf*2+par (0..5), V: 6+...
  __shared__ alignas(16) float mls[4 * 2 * 64];

  const int x = blockIdx.x, bh = blockIdx.y;
  const int tid = threadIdx.x, w = tid >> 6, l = tid & 63;
  const int lq = l & 31, hi = l >> 5;
  const int c  = w >> 2;
  const int st = (w >> 1) & 1;
  const int gc = w & 1;
  const int kind = w >> 2, sp = (w >> 1) & 1, shf = w & 1;

  const __bf16* Qh = Q + (size_t)bh * T_SEQ * HD;
  const __bf16* Kh = K + (size_t)bh * T_SEQ * HD;
  const __bf16* Vh = Vt + (size_t)bh * HD * T_SEQ;

  const int C = (c == 0) ? (31 - x) : x;
  const int q0 = C * 64 + st * 32;
  const int diagT = 2 * C + st;
  const int nsup = 32 - x;

  bf16x8 qf[4];
#pragma unroll
  for (int dc = 0; dc < 4; ++dc)
    qf[dc] = *(const bf16x8*)(Qh + (size_t)(q0 + lq) * HD + dc * 16 + hi * 8);

  f32x16 o0 = {}, o1 = {};
  float m = -1e30f, ls = 0.f;

  const int r8 = l >> 3;
  const int kswz = ((l & 7) ^ r8) * 8;
  const int r4 = l >> 2;
  const int vswz = ((l & 3) ^ (r4 & 3)) * 8;

  auto stage = [&](int buf, int ss) {
    int t = 2 * ss + sp;
    int k0s = t * 32;
    if (kind == 0) {       // K tile: 32 rows(k) x 64(d); half shf = 16 rows
      __bf16* dst = &sKV[buf * 2 + sp][shf * 16 * 64];
#pragma unroll
      for (int i = 0; i < 2; ++i)
        gload_lds16(Kh + (size_t)(k0s + shf * 16 + i * 8 + r8) * HD + kswz,
                    dst + i * 512);
    } else {               // V^T tile: 64 rows(d) x 32(k); half shf = 32 rows
      __bf16* dst = &sKV[6 + buf * 2 + sp][shf * 32 * 32];
#pragma unroll
      for (int i = 0; i < 2; ++i)
        gload_lds16(Vh + (size_t)(shf * 32 + i * 16 + r4) * T_SEQ + k0s + vswz,
                    dst + i * 512);
    }
  };

  auto kfrag = [&](const __bf16* b, int row, int u) -> bf16x8 {
    return *(const bf16x8*)(b + row * 64 + ((u ^ (row & 7)) << 3));
  };
  auto vfrag = [&](const __bf16* b, int row, int u) -> bf16x8 {
    return *(const bf16x8*)(b + row * 32 + ((u ^ (row & 3)) << 3));
  };

  stage(0, 0);
  stage(1, 1);           // nsup >= 17, always valid

  int buf = 0;
  for (int ss = 0; ss < nsup; ++ss) {
    // wait this superstep's OWN 2 loads; next superstep's stay in flight
    if (ss + 1 < nsup) { asm volatile("s_waitcnt vmcnt(2)" ::: "memory"); }
    else               { asm volatile("s_waitcnt vmcnt(0)" ::: "memory"); }
    __builtin_amdgcn_s_barrier();
    __builtin_amdgcn_sched_barrier(0);

    if (ss + 2 < nsup) {
      int bs = buf + 2; if (bs >= 3) bs -= 3;
      stage(bs, ss + 2);
    }

    const int tg = 2 * ss + gc;
    if (tg <= diagT) {
      const __bf16* sKb = &sKV[buf * 2 + gc][0];
      const __bf16* sVb = &sKV[6 + buf * 2 + gc][0];
      f32x16 s = {};
      __builtin_amdgcn_s_setprio(1);
#pragma unroll
      for (int dc = 0; dc < 4; ++dc)
        s = mfma32(kfrag(sKb, lq, dc * 2 + hi), qf[dc], s);
      __builtin_amdgcn_s_setprio(0);
      if (tg == diagT) cmask32(s, tg * 32, hi, q0 + lq);
      u32x4 pf[2];
      softmax_pack32(s, o0, o1, m, ls, pf);
      __builtin_amdgcn_s_setprio(1);
#pragma unroll
      for (int ks = 0; ks < 2; ++ks) {
        bf16x8 vf0 = vfrag(sVb, lq, ks * 2 + hi);
        bf16x8 vf1 = vfrag(sVb, 32 + lq, ks * 2 + hi);
        bf16x8 pa = __builtin_bit_cast(bf16x8, pf[ks]);
        o0 = mfma32(vf0, pa, o0);
        o1 = mfma32(vf1, pa, o1);
      }
      __builtin_amdgcn_s_setprio(0);
    }
    if (++buf >= 3) buf = 0;
  }

  // ---- cross-parity merge (gc=1 dumps, gc=0 merges + stores) ----
  __syncthreads();                  // full drain before aliasing sKV
  float* mo = (float*)&sKV[0][0];   // 4 regions x 2048 f32 = 32 KiB
  const int reg = c * 2 + st;
  if (gc == 1) dump_state(mo, mls, reg, l, o0, o1, m, ls);
  __syncthreads();
  if (gc == 0) {
    const int b = bh >> 4, h = bh & 15;
    size_t row = (size_t)(b * T_SEQ + q0 + lq) * EMB + h * HD;
    merge_write(mo, mls, reg, l, hi, o0, o1, m, ls, O, row);
  }
}

extern "C" void kernel_launch(void* const* d_in, const int* in_sizes, int n_in,
                              void* d_out, int out_size, void* d_ws, size_t ws_size,
                              hipStream_t stream) {
  const float* x      = (const float*)d_in[0];
  const float* w_qkv  = (const float*)d_in[1];
  const float* w_proj = (const float*)d_in[2];
  const float* b_proj = (const float*)d_in[3];
  float* out = (float*)d_out;

  char* ws = (char*)d_ws;
  __bf16* xb     = (__bf16*)(ws);                     // 8 MiB
  __bf16* wqkvT  = (__bf16*)(ws + (8u  << 20));       // 6 MiB
  __bf16* wprojT = (__bf16*)(ws + (14u << 20));       // 2 MiB
  __bf16* Qw     = (__bf16*)(ws + (16u << 20));       // 8 MiB
  __bf16* Kw     = (__bf16*)(ws + (24u << 20));       // 8 MiB
  __bf16* Vw     = (__bf16*)(ws + (32u << 20));       // 8 MiB
  __bf16* Ow     = xb;                                // reuse after QKV GEMM

  cvt_bf16<<<2048, 256, 0, stream>>>(x, xb, 4096 * 1024);
  transpose_cvt<<<dim3(3072 / 32, 1024 / 32), 256, 0, stream>>>(w_qkv, wqkvT, 1024, 3072);
  transpose_cvt<<<dim3(1024 / 32, 1024 / 32), 256, 0, stream>>>(w_proj, wprojT, 1024, 1024);

  gemm_bt<0><<<dim3(3072 / 128, 4096 / 128), 256, 0, stream>>>(
      xb, wqkvT, 1024, Qw, Kw, Vw, nullptr, nullptr);

  attn<<<dim3(16, BATCH * NH), 512, 0, stream>>>(Qw, Kw, Vw, Ow);

  gemm_proj<<<dim3(1024 / 64, 4096 / 128), 256, 0, stream>>>(
      Ow, wprojT, 1024, b_proj, out);
}

// Round 18
// 115.349 us; speedup vs baseline: 1.1325x; 1.0304x over previous
//
#include <hip/hip_runtime.h>

typedef __bf16 bf16x8 __attribute__((ext_vector_type(8)));
typedef __bf16 bf16x4 __attribute__((ext_vector_type(4)));
typedef float  f32x4  __attribute__((ext_vector_type(4)));
typedef float  f32x16 __attribute__((ext_vector_type(16)));
typedef unsigned u32x2 __attribute__((ext_vector_type(2)));
typedef unsigned u32x4 __attribute__((ext_vector_type(4)));

#define T_SEQ 2048
#define NH    16
#define HD    64
#define EMB   1024
#define BATCH 2
// 1/sqrt(HD) * log2(e) — softmax in base 2
#define QSCALE 0.18033688f

__device__ __forceinline__ void gload_lds16(const void* g, void* lds) {
  __builtin_amdgcn_global_load_lds(
      (__attribute__((address_space(1))) void*)(g),
      (__attribute__((address_space(3))) void*)(lds), 16, 0, 0);
}

__device__ __forceinline__ f32x16 mfma32(bf16x8 a, bf16x8 b, f32x16 c) {
  return __builtin_amdgcn_mfma_f32_32x32x16_bf16(a, b, c, 0, 0, 0);
}

__device__ __forceinline__ f32x4 mfma16(bf16x8 a, bf16x8 b, f32x4 c) {
  return __builtin_amdgcn_mfma_f32_16x16x32_bf16(a, b, c, 0, 0, 0);
}

__device__ __forceinline__ unsigned cvtpk(float lo, float hi) {
  unsigned short a = __builtin_bit_cast(unsigned short, (__bf16)lo);
  unsigned short b = __builtin_bit_cast(unsigned short, (__bf16)hi);
  return (unsigned)a | ((unsigned)b << 16);
}

// ---- fp32 -> bf16 straight convert ----
__global__ __launch_bounds__(256) void cvt_bf16(const float* __restrict__ in,
                                                __bf16* __restrict__ out, int n) {
  int i = (blockIdx.x * 256 + threadIdx.x) * 8;
  if (i >= n) return;
  f32x4 a = *(const f32x4*)(in + i);
  f32x4 b = *(const f32x4*)(in + i + 4);
  bf16x8 v;
  v[0] = (__bf16)a[0]; v[1] = (__bf16)a[1]; v[2] = (__bf16)a[2]; v[3] = (__bf16)a[3];
  v[4] = (__bf16)b[0]; v[5] = (__bf16)b[1]; v[6] = (__bf16)b[2]; v[7] = (__bf16)b[3];
  *(bf16x8*)(out + i) = v;
}

// ---- fp32 [rows][cols] -> bf16 [cols][rows] ----
__global__ __launch_bounds__(256) void transpose_cvt(const float* __restrict__ in,
                                                     __bf16* __restrict__ out,
                                                     int rows, int cols) {
  __shared__ float tile[32][33];
  int c0 = blockIdx.x * 32, r0 = blockIdx.y * 32;
  int tx = threadIdx.x & 31, ty = threadIdx.x >> 5;
#pragma unroll
  for (int j = 0; j < 32; j += 8)
    tile[ty + j][tx] = in[(size_t)(r0 + ty + j) * cols + c0 + tx];
  __syncthreads();
#pragma unroll
  for (int j = 0; j < 32; j += 8)
    out[(size_t)(c0 + ty + j) * rows + r0 + tx] = (__bf16)tile[tx][ty + j];
}

// ---- gemm_bt: C[M,N] = A[M,K] * Bt[N,K]^T, 128x128 tile, BK=32, 4 waves ----
// Triple-buffered LDS, counted vmcnt(4); both-sides XOR swizzle.
// MODE 0: QKV scatter epilogue with vectorized V-part stores (r14/r15 proven).
template <int MODE>
__global__ __launch_bounds__(256) void gemm_bt(
    const __bf16* __restrict__ A, const __bf16* __restrict__ Bt, int K,
    __bf16* __restrict__ Qo, __bf16* __restrict__ Ko, __bf16* __restrict__ Vt,
    const float* __restrict__ bias, float* __restrict__ Cout) {
  __shared__ alignas(16) __bf16 sA[3][128 * 32];
  __shared__ alignas(16) __bf16 sB[3][128 * 32];
  const int tid = threadIdx.x;
  const int w = tid >> 6, l = tid & 63;
  const int m0 = blockIdx.y * 128, n0 = blockIdx.x * 128;
  const int lc = l & 15, lu = l >> 4;
  const int mw = (w >> 1) * 64, nw = (w & 1) * 64;
  const int rA = l >> 2;
  const int usw = (((l & 3) ^ ((rA >> 1) & 3))) * 8;
  const int rsw = (lu ^ ((lc >> 1) & 3)) * 8;

  f32x4 acc[4][4] = {};

  auto stage = [&](int buf, int kt) {
#pragma unroll
    for (int i = 0; i < 2; ++i) {
      int rr = (w * 2 + i) * 16;
      gload_lds16(A  + (size_t)(m0 + rr + rA) * K + kt + usw, &sA[buf][rr * 32]);
      gload_lds16(Bt + (size_t)(n0 + rr + rA) * K + kt + usw, &sB[buf][rr * 32]);
    }
  };

  const int NT = K >> 5;
  stage(0, 0);
  stage(1, 32);

  int bi = 0;
  for (int i = 0; i < NT; ++i) {
    if (i == NT - 1) { asm volatile("s_waitcnt vmcnt(0)" ::: "memory"); }
    else             { asm volatile("s_waitcnt vmcnt(4)" ::: "memory"); }
    __builtin_amdgcn_s_barrier();
    __builtin_amdgcn_sched_barrier(0);

    if (i + 2 < NT) {
      int bs = bi + 2; if (bs >= 3) bs -= 3;
      stage(bs, (i + 2) * 32);
    }

    bf16x8 af[4], bfr[4];
#pragma unroll
    for (int f = 0; f < 4; ++f) {
      af[f]  = *(const bf16x8*)(&sA[bi][(mw + f * 16 + lc) * 32 + rsw]);
      bfr[f] = *(const bf16x8*)(&sB[bi][(nw + f * 16 + lc) * 32 + rsw]);
    }
#pragma unroll
    for (int mf = 0; mf < 4; ++mf)
#pragma unroll
      for (int nf = 0; nf < 4; ++nf)
        acc[mf][nf] = mfma16(af[mf], bfr[nf], acc[mf][nf]);

    if (++bi >= 3) bi = 0;
  }

#pragma unroll
  for (int mf = 0; mf < 4; ++mf) {
#pragma unroll
    for (int nf = 0; nf < 4; ++nf) {
      if (MODE == 0) {
        int ng = n0 + nw + nf * 16 + lc;
        int part = ng >> 10;
        int h = (ng >> 6) & 15;
        int d = ng & 63;
        int mg0 = m0 + mw + mf * 16 + lu * 4;
        int b = mg0 >> 11;
        int t0 = mg0 & 2047;
        if (part == 2) {
          bf16x4 v4;
#pragma unroll
          for (int r = 0; r < 4; ++r) v4[r] = (__bf16)acc[mf][nf][r];
          *(bf16x4*)(Vt + ((size_t)(b * NH + h) * HD + d) * T_SEQ + t0) = v4;
        } else if (part == 0) {
#pragma unroll
          for (int r = 0; r < 4; ++r)
            Qo[((size_t)(b * NH + h) * T_SEQ + t0 + r) * HD + d] =
                (__bf16)(acc[mf][nf][r] * QSCALE);
        } else {
#pragma unroll
          for (int r = 0; r < 4; ++r)
            Ko[((size_t)(b * NH + h) * T_SEQ + t0 + r) * HD + d] =
                (__bf16)acc[mf][nf][r];
        }
      } else {
#pragma unroll
        for (int r = 0; r < 4; ++r) {
          int mg = m0 + mw + mf * 16 + lu * 4 + r;
          int ng = n0 + nw + nf * 16 + lc;
          Cout[(size_t)mg * EMB + ng] = acc[mf][nf][r] + bias[ng];
        }
      }
    }
  }
}

// ---- gemm_proj: C[M,N] = A[M,K]*Bt[N,K]^T + bias, 128(M)x64(N) tile ----
__global__ __launch_bounds__(256) void gemm_proj(
    const __bf16* __restrict__ A, const __bf16* __restrict__ Bt, int K,
    const float* __restrict__ bias, float* __restrict__ Cout) {
  __shared__ alignas(16) __bf16 sA[3][128 * 32];
  __shared__ alignas(16) __bf16 sB[3][64 * 32];
  const int tid = threadIdx.x;
  const int w = tid >> 6, l = tid & 63;
  const int m0 = blockIdx.y * 128, n0 = blockIdx.x * 64;
  const int lc = l & 15, lu = l >> 4;
  const int mw = (w >> 1) * 64, nw = (w & 1) * 32;
  const int rA = l >> 2;
  const int usw = (((l & 3) ^ ((rA >> 1) & 3))) * 8;
  const int rsw = (lu ^ ((lc >> 1) & 3)) * 8;

  f32x4 acc[4][2] = {};

  auto stage = [&](int buf, int kt) {
#pragma unroll
    for (int i = 0; i < 2; ++i) {
      int rr = (w * 2 + i) * 16;
      gload_lds16(A + (size_t)(m0 + rr + rA) * K + kt + usw, &sA[buf][rr * 32]);
    }
    gload_lds16(Bt + (size_t)(n0 + w * 16 + rA) * K + kt + usw,
                &sB[buf][w * 16 * 32]);
  };

  const int NT = K >> 5;
  stage(0, 0);
  stage(1, 32);

  int bi = 0;
  for (int i = 0; i < NT; ++i) {
    if (i == NT - 1) { asm volatile("s_waitcnt vmcnt(0)" ::: "memory"); }
    else             { asm volatile("s_waitcnt vmcnt(3)" ::: "memory"); }
    __builtin_amdgcn_s_barrier();
    __builtin_amdgcn_sched_barrier(0);

    if (i + 2 < NT) {
      int bs = bi + 2; if (bs >= 3) bs -= 3;
      stage(bs, (i + 2) * 32);
    }

    bf16x8 af[4], bfr[2];
#pragma unroll
    for (int f = 0; f < 4; ++f)
      af[f] = *(const bf16x8*)(&sA[bi][(mw + f * 16 + lc) * 32 + rsw]);
#pragma unroll
    for (int f = 0; f < 2; ++f)
      bfr[f] = *(const bf16x8*)(&sB[bi][(nw + f * 16 + lc) * 32 + rsw]);
#pragma unroll
    for (int mf = 0; mf < 4; ++mf)
#pragma unroll
      for (int nf = 0; nf < 2; ++nf)
        acc[mf][nf] = mfma16(af[mf], bfr[nf], acc[mf][nf]);

    if (++bi >= 3) bi = 0;
  }

#pragma unroll
  for (int mf = 0; mf < 4; ++mf)
#pragma unroll
    for (int nf = 0; nf < 2; ++nf)
#pragma unroll
      for (int r = 0; r < 4; ++r) {
        int mg = m0 + mw + mf * 16 + lu * 4 + r;
        int ng = n0 + nw + nf * 16 + lc;
        Cout[(size_t)mg * EMB + ng] = acc[mf][nf][r] + bias[ng];
      }
}

// ---- causal mask on one S^T 32x32 tile (rows=k, col=q per lane) ----
__device__ __forceinline__ void cmask32(f32x16& s0, int k0, int hi, int q) {
#pragma unroll
  for (int r = 0; r < 16; ++r) {
    int kk = k0 + 4 * hi + (r & 3) + 8 * (r >> 2);
    if (kk > q) s0[r] = -1e30f;
  }
}

// ---- in-register online softmax + P packing, 32-k tile (T12/T13) ----
__device__ __forceinline__ void softmax_pack32(
    f32x16& s0, f32x16& o0, f32x16& o1,
    float& m, float& ls, u32x4 (&pf)[2]) {
  float mx[8];
#pragma unroll
  for (int r = 0; r < 8; ++r) mx[r] = fmaxf(s0[r], s0[r + 8]);
#pragma unroll
  for (int st = 4; st > 0; st >>= 1)
#pragma unroll
    for (int r = 0; r < 8; ++r) if (r < st) mx[r] = fmaxf(mx[r], mx[r + st]);
  float pmax = fmaxf(mx[0], __shfl_xor(mx[0], 32));
  if (!__all(pmax <= m + 8.0f)) {       // defer-max rescale
    float mn = fmaxf(m, pmax);
    float al = __builtin_amdgcn_exp2f(m - mn);
    m = mn;
    ls *= al;
#pragma unroll
    for (int r = 0; r < 16; ++r) { o0[r] *= al; o1[r] *= al; }
  }
  float ps = 0.f;
  f32x16 p;
#pragma unroll
  for (int r = 0; r < 16; ++r) { p[r] = __builtin_amdgcn_exp2f(s0[r] - m); ps += p[r]; }
  ps += __shfl_xor(ps, 32);
  ls += ps;
#pragma unroll
  for (int kh = 0; kh < 2; ++kh) {
    unsigned c01 = cvtpk(p[kh * 8 + 0], p[kh * 8 + 1]);
    unsigned c23 = cvtpk(p[kh * 8 + 2], p[kh * 8 + 3]);
    unsigned c45 = cvtpk(p[kh * 8 + 4], p[kh * 8 + 5]);
    unsigned c67 = cvtpk(p[kh * 8 + 6], p[kh * 8 + 7]);
    u32x2 a = __builtin_amdgcn_permlane32_swap(c01, c45, false, false);
    u32x2 c = __builtin_amdgcn_permlane32_swap(c23, c67, false, false);
    u32x4 r; r[0] = a[0]; r[1] = c[0]; r[2] = a[1]; r[3] = c[1];
    pf[kh] = r;
  }
}

__device__ __forceinline__ void dump_state(float* mo, float* mm, int reg, int l,
                                           const f32x16& o0, const f32x16& o1,
                                           float m, float ls) {
  float* po = mo + reg * 2048 + l;
#pragma unroll
  for (int r = 0; r < 16; ++r) { po[r * 64] = o0[r]; po[(16 + r) * 64] = o1[r]; }
  mm[reg * 128 + l] = m;
  mm[reg * 128 + 64 + l] = ls;
}

__device__ __forceinline__ void merge_write(const float* mo, const float* mm,
                                            int reg, int l, int hi,
                                            const f32x16& o0, const f32x16& o1,
                                            float m, float ls,
                                            __bf16* O, size_t rowbase) {
  float m1 = mm[reg * 128 + l];
  float l1 = mm[reg * 128 + 64 + l];
  float mn = fmaxf(m, m1);
  float a0 = __builtin_amdgcn_exp2f(m - mn);
  float a1 = __builtin_amdgcn_exp2f(m1 - mn);
  float inv = 1.f / (ls * a0 + l1 * a1);
  const float* po = mo + reg * 2048 + l;
#pragma unroll
  for (int dt = 0; dt < 2; ++dt) {
    const f32x16& ov = dt ? o1 : o0;
#pragma unroll
    for (int rg = 0; rg < 4; ++rg) {
      bf16x4 vv;
#pragma unroll
      for (int j = 0; j < 4; ++j) {
        int r = rg * 4 + j;
        float oth = po[(dt * 16 + r) * 64];
        vv[j] = (__bf16)((ov[r] * a0 + oth * a1) * inv);
      }
      int d = dt * 32 + rg * 8 + 4 * hi;
      *(bf16x4*)(O + rowbase + d) = vv;
    }
  }
}

// ---- causal flash attention: 8-wave blocks, one role per wave,
//      triple-buffered K/V + counted vmcnt(2) (r11, 50.9us) +
//      XCD-locality block remap (T1) + optimal V-read swizzle ----
__global__ __launch_bounds__(512, 4) void attn(
    const __bf16* __restrict__ Q,   // [BH][T][D] pre-scaled by QSCALE
    const __bf16* __restrict__ K,   // [BH][T][D]
    const __bf16* __restrict__ Vt,  // [BH][D][T]
    __bf16* __restrict__ O) {       // [B*T][EMB]
  __shared__ alignas(16) __bf16 sKV[12][32 * 64];  // K: buf*2+par (0..5), V: 6+...
  __shared__ alignas(16) float mls[4 * 2 * 64];

  // XCD-locality remap: all 16 x-blocks of head bh -> linear IDs == bh (mod 8)
  // so they share one XCD's L2 (K/V of 4 heads = 4MB fits the 4MB XCD L2).
  const int lid = blockIdx.x + 16 * blockIdx.y;     // 0..511
  const int bh = (lid & 7) + 8 * (lid >> 7);        // bijective remap
  const int x  = (lid >> 3) & 15;

  const int tid = threadIdx.x, w = tid >> 6, l = tid & 63;
  const int lq = l & 31, hi = l >> 5;
  const int c  = w >> 2;
  const int st = (w >> 1) & 1;
  const int gc = w & 1;
  const int kind = w >> 2, sp = (w >> 1) & 1, shf = w & 1;

  const __bf16* Qh = Q + (size_t)bh * T_SEQ * HD;
  const __bf16* Kh = K + (size_t)bh * T_SEQ * HD;
  const __bf16* Vh = Vt + (size_t)bh * HD * T_SEQ;

  const int C = (c == 0) ? (31 - x) : x;
  const int q0 = C * 64 + st * 32;
  const int diagT = 2 * C + st;
  const int nsup = 32 - x;

  bf16x8 qf[4];
#pragma unroll
  for (int dc = 0; dc < 4; ++dc)
    qf[dc] = *(const bf16x8*)(Qh + (size_t)(q0 + lq) * HD + dc * 16 + hi * 8);

  f32x16 o0 = {}, o1 = {};
  float m = -1e30f, ls = 0.f;

  const int r8 = l >> 3;
  const int kswz = ((l & 7) ^ r8) * 8;
  const int r4 = l >> 2;
  const int vswz = ((l & 3) ^ ((r4 >> 1) & 3)) * 8;   // optimal V swizzle

  auto stage = [&](int buf, int ss) {
    int t = 2 * ss + sp;
    int k0s = t * 32;
    if (kind == 0) {       // K tile: 32 rows(k) x 64(d); half shf = 16 rows
      __bf16* dst = &sKV[buf * 2 + sp][shf * 16 * 64];
#pragma unroll
      for (int i = 0; i < 2; ++i)
        gload_lds16(Kh + (size_t)(k0s + shf * 16 + i * 8 + r8) * HD + kswz,
                    dst + i * 512);
    } else {               // V^T tile: 64 rows(d) x 32(k); half shf = 32 rows
      __bf16* dst = &sKV[6 + buf * 2 + sp][shf * 32 * 32];
#pragma unroll
      for (int i = 0; i < 2; ++i)
        gload_lds16(Vh + (size_t)(shf * 32 + i * 16 + r4) * T_SEQ + k0s + vswz,
                    dst + i * 512);
    }
  };

  auto kfrag = [&](const __bf16* b, int row, int u) -> bf16x8 {
    return *(const bf16x8*)(b + row * 64 + ((u ^ (row & 7)) << 3));
  };
  auto vfrag = [&](const __bf16* b, int row, int u) -> bf16x8 {
    return *(const bf16x8*)(b + row * 32 + ((u ^ ((row >> 1) & 3)) << 3));
  };

  stage(0, 0);
  stage(1, 1);           // nsup >= 17, always valid

  int buf = 0;
  for (int ss = 0; ss < nsup; ++ss) {
    // wait this superstep's OWN 2 loads; next superstep's stay in flight
    if (ss + 1 < nsup) { asm volatile("s_waitcnt vmcnt(2)" ::: "memory"); }
    else               { asm volatile("s_waitcnt vmcnt(0)" ::: "memory"); }
    __builtin_amdgcn_s_barrier();
    __builtin_amdgcn_sched_barrier(0);

    if (ss + 2 < nsup) {
      int bs = buf + 2; if (bs >= 3) bs -= 3;
      stage(bs, ss + 2);
    }

    const int tg = 2 * ss + gc;
    if (tg <= diagT) {
      const __bf16* sKb = &sKV[buf * 2 + gc][0];
      const __bf16* sVb = &sKV[6 + buf * 2 + gc][0];
      f32x16 s = {};
#pragma unroll
      for (int dc = 0; dc < 4; ++dc)
        s = mfma32(kfrag(sKb, lq, dc * 2 + hi), qf[dc], s);
      if (tg == diagT) cmask32(s, tg * 32, hi, q0 + lq);
      u32x4 pf[2];
      softmax_pack32(s, o0, o1, m, ls, pf);
#pragma unroll
      for (int ks = 0; ks < 2; ++ks) {
        bf16x8 vf0 = vfrag(sVb, lq, ks * 2 + hi);
        bf16x8 vf1 = vfrag(sVb, 32 + lq, ks * 2 + hi);
        bf16x8 pa = __builtin_bit_cast(bf16x8, pf[ks]);
        o0 = mfma32(vf0, pa, o0);
        o1 = mfma32(vf1, pa, o1);
      }
    }
    if (++buf >= 3) buf = 0;
  }

  // ---- cross-parity merge (gc=1 dumps, gc=0 merges + stores) ----
  __syncthreads();                  // full drain before aliasing sKV
  float* mo = (float*)&sKV[0][0];   // 4 regions x 2048 f32 = 32 KiB
  const int reg = c * 2 + st;
  if (gc == 1) dump_state(mo, mls, reg, l, o0, o1, m, ls);
  __syncthreads();
  if (gc == 0) {
    const int b = bh >> 4, h = bh & 15;
    size_t row = (size_t)(b * T_SEQ + q0 + lq) * EMB + h * HD;
    merge_write(mo, mls, reg, l, hi, o0, o1, m, ls, O, row);
  }
}

extern "C" void kernel_launch(void* const* d_in, const int* in_sizes, int n_in,
                              void* d_out, int out_size, void* d_ws, size_t ws_size,
                              hipStream_t stream) {
  const float* x      = (const float*)d_in[0];
  const float* w_qkv  = (const float*)d_in[1];
  const float* w_proj = (const float*)d_in[2];
  const float* b_proj = (const float*)d_in[3];
  float* out = (float*)d_out;

  char* ws = (char*)d_ws;
  __bf16* xb     = (__bf16*)(ws);                     // 8 MiB
  __bf16* wqkvT  = (__bf16*)(ws + (8u  << 20));       // 6 MiB
  __bf16* wprojT = (__bf16*)(ws + (14u << 20));       // 2 MiB
  __bf16* Qw     = (__bf16*)(ws + (16u << 20));       // 8 MiB
  __bf16* Kw     = (__bf16*)(ws + (24u << 20));       // 8 MiB
  __bf16* Vw     = (__bf16*)(ws + (32u << 20));       // 8 MiB
  __bf16* Ow     = xb;                                // reuse after QKV GEMM

  cvt_bf16<<<2048, 256, 0, stream>>>(x, xb, 4096 * 1024);
  transpose_cvt<<<dim3(3072 / 32, 1024 / 32), 256, 0, stream>>>(w_qkv, wqkvT, 1024, 3072);
  transpose_cvt<<<dim3(1024 / 32, 1024 / 32), 256, 0, stream>>>(w_proj, wprojT, 1024, 1024);

  gemm_bt<0><<<dim3(3072 / 128, 4096 / 128), 256, 0, stream>>>(
      xb, wqkvT, 1024, Qw, Kw, Vw, nullptr, nullptr);

  attn<<<dim3(16, BATCH * NH), 512, 0, stream>>>(Qw, Kw, Vw, Ow);

  gemm_proj<<<dim3(1024 / 64, 4096 / 128), 256, 0, stream>>>(
      Ow, wprojT, 1024, b_proj, out);
}